// Round 1
// baseline (1328.730 us; speedup 1.0000x reference)
//
#include <hip/hip_runtime.h>
#include <hip/hip_bf16.h>
#include <math.h>

#define D 256
#define NCAM 500
#define NPT 100000

// ---------------- histogram of edge -> point / cam --------------------------
__global__ void hist_kernel(const int* __restrict__ ci, const int* __restrict__ pi,
                            int* __restrict__ cnt_pt, int* __restrict__ cnt_cam, int E) {
    int i = blockIdx.x * 256 + threadIdx.x;
    if (i < E) {
        atomicAdd(&cnt_pt[pi[i]], 1);
        atomicAdd(&cnt_cam[ci[i]], 1);
    }
}

// ---------------- single-block exclusive scan: points (100000) + cams (500) -
__global__ __launch_bounds__(1024) void scan_kernel(const int* __restrict__ cnt_pt,
                                                    const int* __restrict__ cnt_cam,
                                                    int* __restrict__ off_pt,
                                                    int* __restrict__ cur_pt,
                                                    int* __restrict__ off_cam,
                                                    int* __restrict__ cur_cam) {
    __shared__ int lds[1024];
    int t = threadIdx.x;
    const int CH = (NPT + 1023) / 1024;  // 98
    int b0 = t * CH;
    int b1 = b0 + CH; if (b1 > NPT) b1 = NPT;
    int s = 0;
    for (int i = b0; i < b1; i++) s += cnt_pt[i];
    lds[t] = s;
    __syncthreads();
    // inclusive Hillis-Steele over 1024 thread-sums
    for (int off = 1; off < 1024; off <<= 1) {
        int v = (t >= off) ? lds[t - off] : 0;
        __syncthreads();
        lds[t] += v;
        __syncthreads();
    }
    int run = (t == 0) ? 0 : lds[t - 1];
    for (int i = b0; i < b1; i++) {
        int c = cnt_pt[i];
        off_pt[i] = run;
        cur_pt[i] = run;
        run += c;
    }
    if (t == 1023) off_pt[NPT] = lds[1023];
    __syncthreads();
    // cams: 512-wide scan
    if (t < 512) lds[t] = (t < NCAM) ? cnt_cam[t] : 0;
    __syncthreads();
    for (int off = 1; off < 512; off <<= 1) {
        int v = 0;
        if (t < 512 && t >= off) v = lds[t - off];
        __syncthreads();
        if (t < 512 && t >= off) lds[t] += v;
        __syncthreads();
    }
    if (t < NCAM) {
        int ex = (t == 0) ? 0 : lds[t - 1];
        off_cam[t] = ex;
        cur_cam[t] = ex;
    }
    if (t == NCAM) off_cam[NCAM] = lds[NCAM - 1];
}

// ---------------- bucket: edge ids grouped by point and by cam --------------
__global__ void bucket_kernel(const int* __restrict__ ci, const int* __restrict__ pi,
                              int* __restrict__ cur_pt, int* __restrict__ cur_cam,
                              int* __restrict__ order_pt, int* __restrict__ order_cam,
                              int E) {
    int i = blockIdx.x * 256 + threadIdx.x;
    if (i < E) {
        int pos = atomicAdd(&cur_pt[pi[i]], 1);
        order_pt[pos] = i;
        int pos2 = atomicAdd(&cur_cam[ci[i]], 1);
        order_cam[pos2] = i;
    }
}

// ---------------- point aggregation by gather (1 wave/point, float4/lane),
//                  fused apt[p] = pt_agg[p,:] . vpt --------------------------
__global__ void pt_agg_kernel(const float* __restrict__ ef,
                              const int* __restrict__ order_pt,
                              const int* __restrict__ off_pt,
                              const float* __restrict__ vpt,
                              float* __restrict__ pt_agg,
                              float* __restrict__ apt) {
    int wave = threadIdx.x >> 6;
    int lane = threadIdx.x & 63;
    int p = blockIdx.x * 4 + wave;
    if (p >= NPT) return;
    int j0 = off_pt[p], j1 = off_pt[p + 1];
    float4 acc = make_float4(0.f, 0.f, 0.f, 0.f);
    for (int j = j0; j < j1; j++) {
        int e = order_pt[j];
        float4 v = *(const float4*)(ef + (size_t)e * D + lane * 4);
        acc.x += v.x; acc.y += v.y; acc.z += v.z; acc.w += v.w;
    }
    *(float4*)(pt_agg + (size_t)p * D + lane * 4) = acc;
    float4 vv = *(const float4*)(vpt + lane * 4);
    float d = acc.x * vv.x + acc.y * vv.y + acc.z * vv.z + acc.w * vv.w;
    for (int off = 32; off > 0; off >>= 1) d += __shfl_down(d, off);
    if (lane == 0) apt[p] = d;
}

// ---------------- cam aggregation by gather (500 x 8 blocks, thread=feature)
__global__ void cam_agg_kernel(const float* __restrict__ ef,
                               const int* __restrict__ order_cam,
                               const int* __restrict__ off_cam,
                               float* __restrict__ cam_agg) {
    int c = blockIdx.x;
    int q = blockIdx.y;      // 0..7 slice of this cam's edge list
    int t = threadIdx.x;     // feature
    int j0 = off_cam[c], j1 = off_cam[c + 1];
    float acc = 0.f;
    for (int j = j0 + q; j < j1; j += 8) {
        int e = order_cam[j];
        acc += ef[(size_t)e * D + t];
    }
    atomicAdd(&cam_agg[(size_t)c * D + t], acc);
}

// ---------------- fold weights (unchanged) ----------------------------------
__global__ void combine_weights(const float* __restrict__ Wcam,
                                const float* __restrict__ Wpt,
                                const float* __restrict__ Wattn,
                                const float* __restrict__ Wfin,
                                float* __restrict__ CcamT,
                                float* __restrict__ Cpt,
                                float* __restrict__ vcam,
                                float* __restrict__ vpt) {
    int b = blockIdx.x;
    int i = threadIdx.x;
    if (b < 256) {
        int o = b;
        float acc = 0.f;
        for (int j = 0; j < 256; j++) acc += Wfin[o * 512 + j] * Wcam[j * 256 + i];
        CcamT[i * 256 + o] = acc;
    } else if (b < 512) {
        int o = b - 256;
        float acc = 0.f;
        for (int j = 0; j < 256; j++) acc += Wfin[o * 512 + 256 + j] * Wpt[j * 256 + i];
        Cpt[o * 256 + i] = acc;
    } else if (b == 512) {
        float acc = 0.f;
        for (int j = 0; j < 256; j++) acc += Wattn[j] * Wcam[j * 256 + i];
        vcam[i] = acc;
    } else {
        float acc = 0.f;
        for (int j = 0; j < 256; j++) acc += Wattn[256 + j] * Wpt[j * 256 + i];
        vpt[i] = acc;
    }
}

// ---------------- cam projection (unchanged) --------------------------------
__global__ void cam_proj(const float* __restrict__ cam_agg,
                         const float* __restrict__ CcamT,
                         const float* __restrict__ vcam,
                         float* __restrict__ gcam,
                         float* __restrict__ acam) {
    __shared__ float row[256];
    __shared__ float red[256];
    int c = blockIdx.x;
    int t = threadIdx.x;
    row[t] = cam_agg[(size_t)c * 256 + t];
    __syncthreads();
    float acc = 0.f;
    for (int i = 0; i < 256; i++) acc += row[i] * CcamT[i * 256 + t];
    gcam[(size_t)c * 256 + t] = acc;
    red[t] = row[t] * vcam[t];
    __syncthreads();
    for (int s = 128; s > 0; s >>= 1) {
        if (t < s) red[t] += red[t + s];
        __syncthreads();
    }
    if (t == 0) acam[c] = red[0];
}

// ---------------- main GEMM (unchanged) -------------------------------------
#define BM 64
#define BN 64
#define BK 32
__global__ __launch_bounds__(256) void gemm_pt(const float* __restrict__ A,
                                               const float* __restrict__ Bmat,
                                               float* __restrict__ Cout, int M) {
    __shared__ float As[BK][BM + 4];
    __shared__ float Bs[BK][BN + 4];
    int m0 = blockIdx.x * BM;
    int n0 = blockIdx.y * BN;
    int tid = threadIdx.x;
    int arow = tid >> 2;
    int acol = (tid & 3) * 8;
    int tm = (tid >> 4) << 2;
    int tn = (tid & 15) << 2;
    float acc[4][4] = {};
    for (int k0 = 0; k0 < 256; k0 += BK) {
        const float* aptr = A + (size_t)(m0 + arow) * 256 + k0 + acol;
        float4 av0 = *(const float4*)aptr;
        float4 av1 = *(const float4*)(aptr + 4);
        const float* bptr = Bmat + (size_t)(n0 + arow) * 256 + k0 + acol;
        float4 bv0 = *(const float4*)bptr;
        float4 bv1 = *(const float4*)(bptr + 4);
        As[acol + 0][arow] = av0.x; As[acol + 1][arow] = av0.y;
        As[acol + 2][arow] = av0.z; As[acol + 3][arow] = av0.w;
        As[acol + 4][arow] = av1.x; As[acol + 5][arow] = av1.y;
        As[acol + 6][arow] = av1.z; As[acol + 7][arow] = av1.w;
        Bs[acol + 0][arow] = bv0.x; Bs[acol + 1][arow] = bv0.y;
        Bs[acol + 2][arow] = bv0.z; Bs[acol + 3][arow] = bv0.w;
        Bs[acol + 4][arow] = bv1.x; Bs[acol + 5][arow] = bv1.y;
        Bs[acol + 6][arow] = bv1.z; Bs[acol + 7][arow] = bv1.w;
        __syncthreads();
#pragma unroll
        for (int k = 0; k < BK; k++) {
            float4 a = *(const float4*)&As[k][tm];
            float4 b = *(const float4*)&Bs[k][tn];
            acc[0][0] += a.x * b.x; acc[0][1] += a.x * b.y; acc[0][2] += a.x * b.z; acc[0][3] += a.x * b.w;
            acc[1][0] += a.y * b.x; acc[1][1] += a.y * b.y; acc[1][2] += a.y * b.z; acc[1][3] += a.y * b.w;
            acc[2][0] += a.z * b.x; acc[2][1] += a.z * b.y; acc[2][2] += a.z * b.z; acc[2][3] += a.z * b.w;
            acc[3][0] += a.w * b.x; acc[3][1] += a.w * b.y; acc[3][2] += a.w * b.z; acc[3][3] += a.w * b.w;
        }
        __syncthreads();
    }
#pragma unroll
    for (int i = 0; i < 4; i++) {
        int m = m0 + tm + i;
        if (m < M) {
            float4 v = make_float4(acc[i][0], acc[i][1], acc[i][2], acc[i][3]);
            *(float4*)&Cout[(size_t)m * 256 + n0 + tn] = v;
        }
    }
}

// ---------------- e + global max (monotonic-uint atomicMax) -----------------
__device__ __forceinline__ unsigned float_key(float f) {
    unsigned b = __float_as_uint(f);
    return (b & 0x80000000u) ? ~b : (b | 0x80000000u);
}
__device__ __forceinline__ float key_float(unsigned k) {
    return __uint_as_float((k & 0x80000000u) ? (k & 0x7FFFFFFFu) : ~k);
}

__global__ void e_max_kernel(const int* __restrict__ ci, const int* __restrict__ pi,
                             const float* __restrict__ acam, const float* __restrict__ apt,
                             float* __restrict__ ebuf, unsigned* __restrict__ maxkey, int E) {
    int i = blockIdx.x * 256 + threadIdx.x;
    float e = -INFINITY;
    if (i < E) {
        e = acam[ci[i]] + apt[pi[i]];
        ebuf[i] = e;
    }
    __shared__ float red[256];
    int t = threadIdx.x;
    red[t] = e;
    __syncthreads();
    for (int s = 128; s > 0; s >>= 1) {
        if (t < s) red[t] = fmaxf(red[t], red[t + s]);
        __syncthreads();
    }
    if (t == 0) atomicMax(maxkey, float_key(red[0]));
}

__global__ void sumexp_kernel(float* __restrict__ ebuf,
                              const unsigned* __restrict__ maxkey,
                              float* __restrict__ sumexp, int E) {
    int i = blockIdx.x * 256 + threadIdx.x;
    float mx = key_float(*maxkey);
    float p = 0.f;
    if (i < E) {
        p = expf(ebuf[i] - mx);
        ebuf[i] = p;
    }
    __shared__ float red[256];
    int t = threadIdx.x;
    red[t] = p;
    __syncthreads();
    for (int s = 128; s > 0; s >>= 1) {
        if (t < s) red[t] += red[t + s];
        __syncthreads();
    }
    if (t == 0) atomicAdd(sumexp, red[0]);
}

// ---------------- output: one edge per block --------------------------------
__global__ void out_kernel(const int* __restrict__ ci, const int* __restrict__ pi,
                           const float* __restrict__ gcam, const float* __restrict__ gpt,
                           const float* __restrict__ bfin, const float* __restrict__ ebuf,
                           const float* __restrict__ sumexp, float* __restrict__ out, int E) {
    int e = blockIdx.x;
    int t = threadIdx.x;
    float scale = ebuf[e] / (*sumexp);
    int c = ci[e];
    int p = pi[e];
    float v = (gcam[(size_t)c * 256 + t] + gpt[(size_t)p * 256 + t] + bfin[t]) * scale;
    out[(size_t)e * 256 + t] = fmaxf(v, 0.f);
}

extern "C" void kernel_launch(void* const* d_in, const int* in_sizes, int n_in,
                              void* d_out, int out_size, void* d_ws, size_t ws_size,
                              hipStream_t stream) {
    const float* ef    = (const float*)d_in[0];
    const int*   ci    = (const int*)d_in[1];
    const int*   pi    = (const int*)d_in[2];
    const float* Wcam  = (const float*)d_in[5];
    const float* Wpt   = (const float*)d_in[6];
    const float* Wattn = (const float*)d_in[7];
    const float* Wfin  = (const float*)d_in[8];
    const float* bfin  = (const float*)d_in[9];
    float* out = (float*)d_out;
    int E = in_sizes[0] / D;

    float* ws = (float*)d_ws;
    float* cam_agg = ws;                              // 128000
    float* pt_agg  = cam_agg + (size_t)NCAM * D;      // 25,600,000
    float* CcamT   = pt_agg + (size_t)NPT * D;        // 65536
    float* Cpt     = CcamT + 65536;                   // 65536
    float* vcam    = Cpt + 65536;                     // 256
    float* vpt     = vcam + 256;                      // 256
    float* gcam    = vpt + 256;                       // 128000
    float* acam    = gcam + (size_t)NCAM * D;         // 512 (padded)
    float* gpt     = acam + 512;                      // 25,600,000
    float* apt     = gpt + (size_t)NPT * D;           // 100000
    float* ebuf    = apt + NPT;                       // E
    unsigned* maxkey = (unsigned*)(ebuf + E);
    float* sumexp  = (float*)(maxkey + 1);

    // counting-sort metadata overlaid on gpt (all consumed before gemm_pt writes gpt)
    int* ib        = (int*)gpt;
    int* cnt_pt    = ib;                      // NPT
    int* cnt_cam   = cnt_pt + NPT;            // NCAM   (contiguous with cnt_pt for one memset)
    int* off_pt    = cnt_cam + NCAM;          // NPT+1
    int* off_cam   = off_pt + NPT + 1;        // NCAM+1
    int* cur_pt    = off_cam + NCAM + 1;      // NPT
    int* cur_cam   = cur_pt + NPT;            // NCAM
    int* order_pt  = cur_cam + NCAM;          // E
    int* order_cam = order_pt + E;            // E

    hipMemsetAsync(cam_agg, 0, (size_t)NCAM * D * sizeof(float), stream);
    hipMemsetAsync(maxkey, 0, 2 * sizeof(unsigned), stream);
    hipMemsetAsync(cnt_pt, 0, (size_t)(NPT + NCAM) * sizeof(int), stream);

    int eb = (E + 255) / 256;
    hist_kernel<<<eb, 256, 0, stream>>>(ci, pi, cnt_pt, cnt_cam, E);
    combine_weights<<<514, 256, 0, stream>>>(Wcam, Wpt, Wattn, Wfin, CcamT, Cpt, vcam, vpt);
    scan_kernel<<<1, 1024, 0, stream>>>(cnt_pt, cnt_cam, off_pt, cur_pt, off_cam, cur_cam);
    bucket_kernel<<<eb, 256, 0, stream>>>(ci, pi, cur_pt, cur_cam, order_pt, order_cam, E);
    pt_agg_kernel<<<(NPT + 3) / 4, 256, 0, stream>>>(ef, order_pt, off_pt, vpt, pt_agg, apt);
    cam_agg_kernel<<<dim3(NCAM, 8), 256, 0, stream>>>(ef, order_cam, off_cam, cam_agg);
    cam_proj<<<NCAM, 256, 0, stream>>>(cam_agg, CcamT, vcam, gcam, acam);
    dim3 g4((NPT + BM - 1) / BM, 256 / BN);
    gemm_pt<<<g4, 256, 0, stream>>>(pt_agg, Cpt, gpt, NPT);
    e_max_kernel<<<eb, 256, 0, stream>>>(ci, pi, acam, apt, ebuf, maxkey, E);
    sumexp_kernel<<<eb, 256, 0, stream>>>(ebuf, maxkey, sumexp, E);
    out_kernel<<<E, 256, 0, stream>>>(ci, pi, gcam, gpt, bfin, ebuf, sumexp, out, E);
}

// Round 2
// 1122.341 us; speedup vs baseline: 1.1839x; 1.1839x over previous
//
#include <hip/hip_runtime.h>
#include <hip/hip_bf16.h>
#include <math.h>

#define D 256
#define NCAM 500
#define NPT 100000
#define SCAN_NB ((NPT + 1023) / 1024)   // 98 blocks of 1024

// ---------------- histogram of edge -> point / cam --------------------------
__global__ void hist_kernel(const int* __restrict__ ci, const int* __restrict__ pi,
                            int* __restrict__ cnt_pt, int* __restrict__ cnt_cam, int E) {
    int i = blockIdx.x * 256 + threadIdx.x;
    if (i < E) {
        atomicAdd(&cnt_pt[pi[i]], 1);
        atomicAdd(&cnt_cam[ci[i]], 1);
    }
}

// ---------------- parallel scan, phase A: per-block reduce ------------------
__global__ __launch_bounds__(1024) void scan_partA(const int* __restrict__ cnt_pt,
                                                   int* __restrict__ blk_sum) {
    __shared__ int lds[1024];
    int t = threadIdx.x;
    int i = blockIdx.x * 1024 + t;
    lds[t] = (i < NPT) ? cnt_pt[i] : 0;
    __syncthreads();
    for (int s = 512; s > 0; s >>= 1) {
        if (t < s) lds[t] += lds[t + s];
        __syncthreads();
    }
    if (t == 0) blk_sum[blockIdx.x] = lds[0];
}

// ---------------- phase B: scan 98 block sums + 500 cam counts (1 block) ----
__global__ __launch_bounds__(512) void scan_partB(const int* __restrict__ blk_sum,
                                                  int* __restrict__ blk_base,
                                                  int* __restrict__ off_pt,
                                                  const int* __restrict__ cnt_cam,
                                                  int* __restrict__ off_cam,
                                                  int* __restrict__ cur_cam) {
    __shared__ int lds[512];
    int t = threadIdx.x;
    lds[t] = (t < SCAN_NB) ? blk_sum[t] : 0;
    __syncthreads();
    for (int off = 1; off < 512; off <<= 1) {
        int v = (t >= off) ? lds[t - off] : 0;
        __syncthreads();
        lds[t] += v;
        __syncthreads();
    }
    if (t < SCAN_NB) blk_base[t] = (t == 0) ? 0 : lds[t - 1];
    if (t == SCAN_NB) off_pt[NPT] = lds[SCAN_NB - 1];   // total = E
    __syncthreads();
    // cams
    lds[t] = (t < NCAM) ? cnt_cam[t] : 0;
    __syncthreads();
    for (int off = 1; off < 512; off <<= 1) {
        int v = (t >= off) ? lds[t - off] : 0;
        __syncthreads();
        lds[t] += v;
        __syncthreads();
    }
    if (t < NCAM) {
        int ex = (t == 0) ? 0 : lds[t - 1];
        off_cam[t] = ex;
        cur_cam[t] = ex;
    }
    if (t == NCAM) off_cam[NCAM] = lds[NCAM - 1];
}

// ---------------- phase C: per-block local scan + base ----------------------
__global__ __launch_bounds__(1024) void scan_partC(const int* __restrict__ cnt_pt,
                                                   const int* __restrict__ blk_base,
                                                   int* __restrict__ off_pt,
                                                   int* __restrict__ cur_pt) {
    __shared__ int lds[1024];
    int t = threadIdx.x;
    int i = blockIdx.x * 1024 + t;
    lds[t] = (i < NPT) ? cnt_pt[i] : 0;
    __syncthreads();
    for (int off = 1; off < 1024; off <<= 1) {
        int v = (t >= off) ? lds[t - off] : 0;
        __syncthreads();
        lds[t] += v;
        __syncthreads();
    }
    if (i < NPT) {
        int ex = blk_base[blockIdx.x] + ((t == 0) ? 0 : lds[t - 1]);
        off_pt[i] = ex;
        cur_pt[i] = ex;
    }
}

// ---------------- bucket: edge ids grouped by point and by cam --------------
__global__ void bucket_kernel(const int* __restrict__ ci, const int* __restrict__ pi,
                              int* __restrict__ cur_pt, int* __restrict__ cur_cam,
                              int* __restrict__ order_pt, int* __restrict__ order_cam,
                              int E) {
    int i = blockIdx.x * 256 + threadIdx.x;
    if (i < E) {
        int pos = atomicAdd(&cur_pt[pi[i]], 1);
        order_pt[pos] = i;
        int pos2 = atomicAdd(&cur_cam[ci[i]], 1);
        order_cam[pos2] = i;
    }
}

// ---------------- point aggregation by gather (1 wave/point, float4/lane),
//                  fused apt[p] = pt_agg[p,:] . vpt --------------------------
__global__ void pt_agg_kernel(const float* __restrict__ ef,
                              const int* __restrict__ order_pt,
                              const int* __restrict__ off_pt,
                              const float* __restrict__ vpt,
                              float* __restrict__ pt_agg,
                              float* __restrict__ apt) {
    int wave = threadIdx.x >> 6;
    int lane = threadIdx.x & 63;
    int p = blockIdx.x * 4 + wave;
    if (p >= NPT) return;
    int j0 = off_pt[p], j1 = off_pt[p + 1];
    float4 acc = make_float4(0.f, 0.f, 0.f, 0.f);
    for (int j = j0; j < j1; j++) {
        int e = order_pt[j];
        float4 v = *(const float4*)(ef + (size_t)e * D + lane * 4);
        acc.x += v.x; acc.y += v.y; acc.z += v.z; acc.w += v.w;
    }
    *(float4*)(pt_agg + (size_t)p * D + lane * 4) = acc;
    float4 vv = *(const float4*)(vpt + lane * 4);
    float d = acc.x * vv.x + acc.y * vv.y + acc.z * vv.z + acc.w * vv.w;
    for (int off = 32; off > 0; off >>= 1) d += __shfl_down(d, off);
    if (lane == 0) apt[p] = d;
}

// ---------------- cam aggregation by gather (500 x 8 blocks, thread=feature)
__global__ void cam_agg_kernel(const float* __restrict__ ef,
                               const int* __restrict__ order_cam,
                               const int* __restrict__ off_cam,
                               float* __restrict__ cam_agg) {
    int c = blockIdx.x;
    int q = blockIdx.y;      // 0..7 slice of this cam's edge list
    int t = threadIdx.x;     // feature
    int j0 = off_cam[c], j1 = off_cam[c + 1];
    float acc = 0.f;
    for (int j = j0 + q; j < j1; j += 8) {
        int e = order_cam[j];
        acc += ef[(size_t)e * D + t];
    }
    atomicAdd(&cam_agg[(size_t)c * D + t], acc);
}

// ---------------- fold weights (unchanged) ----------------------------------
__global__ void combine_weights(const float* __restrict__ Wcam,
                                const float* __restrict__ Wpt,
                                const float* __restrict__ Wattn,
                                const float* __restrict__ Wfin,
                                float* __restrict__ CcamT,
                                float* __restrict__ Cpt,
                                float* __restrict__ vcam,
                                float* __restrict__ vpt) {
    int b = blockIdx.x;
    int i = threadIdx.x;
    if (b < 256) {
        int o = b;
        float acc = 0.f;
        for (int j = 0; j < 256; j++) acc += Wfin[o * 512 + j] * Wcam[j * 256 + i];
        CcamT[i * 256 + o] = acc;
    } else if (b < 512) {
        int o = b - 256;
        float acc = 0.f;
        for (int j = 0; j < 256; j++) acc += Wfin[o * 512 + 256 + j] * Wpt[j * 256 + i];
        Cpt[o * 256 + i] = acc;
    } else if (b == 512) {
        float acc = 0.f;
        for (int j = 0; j < 256; j++) acc += Wattn[j] * Wcam[j * 256 + i];
        vcam[i] = acc;
    } else {
        float acc = 0.f;
        for (int j = 0; j < 256; j++) acc += Wattn[256 + j] * Wpt[j * 256 + i];
        vpt[i] = acc;
    }
}

// ---------------- cam projection (unchanged) --------------------------------
__global__ void cam_proj(const float* __restrict__ cam_agg,
                         const float* __restrict__ CcamT,
                         const float* __restrict__ vcam,
                         float* __restrict__ gcam,
                         float* __restrict__ acam) {
    __shared__ float row[256];
    __shared__ float red[256];
    int c = blockIdx.x;
    int t = threadIdx.x;
    row[t] = cam_agg[(size_t)c * 256 + t];
    __syncthreads();
    float acc = 0.f;
    for (int i = 0; i < 256; i++) acc += row[i] * CcamT[i * 256 + t];
    gcam[(size_t)c * 256 + t] = acc;
    red[t] = row[t] * vcam[t];
    __syncthreads();
    for (int s = 128; s > 0; s >>= 1) {
        if (t < s) red[t] += red[t + s];
        __syncthreads();
    }
    if (t == 0) acam[c] = red[0];
}

// ---------------- main GEMM (unchanged) -------------------------------------
#define BM 64
#define BN 64
#define BK 32
__global__ __launch_bounds__(256) void gemm_pt(const float* __restrict__ A,
                                               const float* __restrict__ Bmat,
                                               float* __restrict__ Cout, int M) {
    __shared__ float As[BK][BM + 4];
    __shared__ float Bs[BK][BN + 4];
    int m0 = blockIdx.x * BM;
    int n0 = blockIdx.y * BN;
    int tid = threadIdx.x;
    int arow = tid >> 2;
    int acol = (tid & 3) * 8;
    int tm = (tid >> 4) << 2;
    int tn = (tid & 15) << 2;
    float acc[4][4] = {};
    for (int k0 = 0; k0 < 256; k0 += BK) {
        const float* aptr = A + (size_t)(m0 + arow) * 256 + k0 + acol;
        float4 av0 = *(const float4*)aptr;
        float4 av1 = *(const float4*)(aptr + 4);
        const float* bptr = Bmat + (size_t)(n0 + arow) * 256 + k0 + acol;
        float4 bv0 = *(const float4*)bptr;
        float4 bv1 = *(const float4*)(bptr + 4);
        As[acol + 0][arow] = av0.x; As[acol + 1][arow] = av0.y;
        As[acol + 2][arow] = av0.z; As[acol + 3][arow] = av0.w;
        As[acol + 4][arow] = av1.x; As[acol + 5][arow] = av1.y;
        As[acol + 6][arow] = av1.z; As[acol + 7][arow] = av1.w;
        Bs[acol + 0][arow] = bv0.x; Bs[acol + 1][arow] = bv0.y;
        Bs[acol + 2][arow] = bv0.z; Bs[acol + 3][arow] = bv0.w;
        Bs[acol + 4][arow] = bv1.x; Bs[acol + 5][arow] = bv1.y;
        Bs[acol + 6][arow] = bv1.z; Bs[acol + 7][arow] = bv1.w;
        __syncthreads();
#pragma unroll
        for (int k = 0; k < BK; k++) {
            float4 a = *(const float4*)&As[k][tm];
            float4 b = *(const float4*)&Bs[k][tn];
            acc[0][0] += a.x * b.x; acc[0][1] += a.x * b.y; acc[0][2] += a.x * b.z; acc[0][3] += a.x * b.w;
            acc[1][0] += a.y * b.x; acc[1][1] += a.y * b.y; acc[1][2] += a.y * b.z; acc[1][3] += a.y * b.w;
            acc[2][0] += a.z * b.x; acc[2][1] += a.z * b.y; acc[2][2] += a.z * b.z; acc[2][3] += a.z * b.w;
            acc[3][0] += a.w * b.x; acc[3][1] += a.w * b.y; acc[3][2] += a.w * b.z; acc[3][3] += a.w * b.w;
        }
        __syncthreads();
    }
#pragma unroll
    for (int i = 0; i < 4; i++) {
        int m = m0 + tm + i;
        if (m < M) {
            float4 v = make_float4(acc[i][0], acc[i][1], acc[i][2], acc[i][3]);
            *(float4*)&Cout[(size_t)m * 256 + n0 + tn] = v;
        }
    }
}

// ---------------- e + global max (monotonic-uint atomicMax) -----------------
__device__ __forceinline__ unsigned float_key(float f) {
    unsigned b = __float_as_uint(f);
    return (b & 0x80000000u) ? ~b : (b | 0x80000000u);
}
__device__ __forceinline__ float key_float(unsigned k) {
    return __uint_as_float((k & 0x80000000u) ? (k & 0x7FFFFFFFu) : ~k);
}

__global__ void e_max_kernel(const int* __restrict__ ci, const int* __restrict__ pi,
                             const float* __restrict__ acam, const float* __restrict__ apt,
                             float* __restrict__ ebuf, unsigned* __restrict__ maxkey, int E) {
    int i = blockIdx.x * 256 + threadIdx.x;
    float e = -INFINITY;
    if (i < E) {
        e = acam[ci[i]] + apt[pi[i]];
        ebuf[i] = e;
    }
    __shared__ float red[256];
    int t = threadIdx.x;
    red[t] = e;
    __syncthreads();
    for (int s = 128; s > 0; s >>= 1) {
        if (t < s) red[t] = fmaxf(red[t], red[t + s]);
        __syncthreads();
    }
    if (t == 0) atomicMax(maxkey, float_key(red[0]));
}

__global__ void sumexp_kernel(float* __restrict__ ebuf,
                              const unsigned* __restrict__ maxkey,
                              float* __restrict__ sumexp, int E) {
    int i = blockIdx.x * 256 + threadIdx.x;
    float mx = key_float(*maxkey);
    float p = 0.f;
    if (i < E) {
        p = expf(ebuf[i] - mx);
        ebuf[i] = p;
    }
    __shared__ float red[256];
    int t = threadIdx.x;
    red[t] = p;
    __syncthreads();
    for (int s = 128; s > 0; s >>= 1) {
        if (t < s) red[t] += red[t + s];
        __syncthreads();
    }
    if (t == 0) atomicAdd(sumexp, red[0]);
}

// ---------------- output: one edge per block --------------------------------
__global__ void out_kernel(const int* __restrict__ ci, const int* __restrict__ pi,
                           const float* __restrict__ gcam, const float* __restrict__ gpt,
                           const float* __restrict__ bfin, const float* __restrict__ ebuf,
                           const float* __restrict__ sumexp, float* __restrict__ out, int E) {
    int e = blockIdx.x;
    int t = threadIdx.x;
    float scale = ebuf[e] / (*sumexp);
    int c = ci[e];
    int p = pi[e];
    float v = (gcam[(size_t)c * 256 + t] + gpt[(size_t)p * 256 + t] + bfin[t]) * scale;
    out[(size_t)e * 256 + t] = fmaxf(v, 0.f);
}

extern "C" void kernel_launch(void* const* d_in, const int* in_sizes, int n_in,
                              void* d_out, int out_size, void* d_ws, size_t ws_size,
                              hipStream_t stream) {
    const float* ef    = (const float*)d_in[0];
    const int*   ci    = (const int*)d_in[1];
    const int*   pi    = (const int*)d_in[2];
    const float* Wcam  = (const float*)d_in[5];
    const float* Wpt   = (const float*)d_in[6];
    const float* Wattn = (const float*)d_in[7];
    const float* Wfin  = (const float*)d_in[8];
    const float* bfin  = (const float*)d_in[9];
    float* out = (float*)d_out;
    int E = in_sizes[0] / D;

    float* ws = (float*)d_ws;
    float* cam_agg = ws;                              // 128000
    float* pt_agg  = cam_agg + (size_t)NCAM * D;      // 25,600,000
    float* CcamT   = pt_agg + (size_t)NPT * D;        // 65536
    float* Cpt     = CcamT + 65536;                   // 65536
    float* vcam    = Cpt + 65536;                     // 256
    float* vpt     = vcam + 256;                      // 256
    float* gcam    = vpt + 256;                       // 128000
    float* acam    = gcam + (size_t)NCAM * D;         // 512 (padded)
    float* gpt     = acam + 512;                      // 25,600,000
    float* apt     = gpt + (size_t)NPT * D;           // 100000
    float* ebuf    = apt + NPT;                       // E
    unsigned* maxkey = (unsigned*)(ebuf + E);
    float* sumexp  = (float*)(maxkey + 1);

    // counting-sort metadata overlaid on gpt (all consumed before gemm_pt writes gpt)
    int* ib        = (int*)gpt;
    int* cnt_pt    = ib;                      // NPT
    int* cnt_cam   = cnt_pt + NPT;            // NCAM   (contiguous with cnt_pt for one memset)
    int* off_pt    = cnt_cam + NCAM;          // NPT+1
    int* off_cam   = off_pt + NPT + 1;        // NCAM+1
    int* cur_pt    = off_cam + NCAM + 1;      // NPT
    int* cur_cam   = cur_pt + NPT;            // NCAM
    int* order_pt  = cur_cam + NCAM;          // E
    int* order_cam = order_pt + E;            // E
    int* blk_sum   = order_cam + E;           // SCAN_NB
    int* blk_base  = blk_sum + SCAN_NB;       // SCAN_NB

    hipMemsetAsync(cam_agg, 0, (size_t)NCAM * D * sizeof(float), stream);
    hipMemsetAsync(maxkey, 0, 2 * sizeof(unsigned), stream);
    hipMemsetAsync(cnt_pt, 0, (size_t)(NPT + NCAM) * sizeof(int), stream);

    int eb = (E + 255) / 256;
    hist_kernel<<<eb, 256, 0, stream>>>(ci, pi, cnt_pt, cnt_cam, E);
    combine_weights<<<514, 256, 0, stream>>>(Wcam, Wpt, Wattn, Wfin, CcamT, Cpt, vcam, vpt);
    scan_partA<<<SCAN_NB, 1024, 0, stream>>>(cnt_pt, blk_sum);
    scan_partB<<<1, 512, 0, stream>>>(blk_sum, blk_base, off_pt, cnt_cam, off_cam, cur_cam);
    scan_partC<<<SCAN_NB, 1024, 0, stream>>>(cnt_pt, blk_base, off_pt, cur_pt);
    bucket_kernel<<<eb, 256, 0, stream>>>(ci, pi, cur_pt, cur_cam, order_pt, order_cam, E);
    pt_agg_kernel<<<(NPT + 3) / 4, 256, 0, stream>>>(ef, order_pt, off_pt, vpt, pt_agg, apt);
    cam_agg_kernel<<<dim3(NCAM, 8), 256, 0, stream>>>(ef, order_cam, off_cam, cam_agg);
    cam_proj<<<NCAM, 256, 0, stream>>>(cam_agg, CcamT, vcam, gcam, acam);
    dim3 g4((NPT + BM - 1) / BM, 256 / BN);
    gemm_pt<<<g4, 256, 0, stream>>>(pt_agg, Cpt, gpt, NPT);
    e_max_kernel<<<eb, 256, 0, stream>>>(ci, pi, acam, apt, ebuf, maxkey, E);
    sumexp_kernel<<<eb, 256, 0, stream>>>(ebuf, maxkey, sumexp, E);
    out_kernel<<<E, 256, 0, stream>>>(ci, pi, gcam, gpt, bfin, ebuf, sumexp, out, E);
}

// Round 4
// 983.164 us; speedup vs baseline: 1.3515x; 1.1416x over previous
//
#include <hip/hip_runtime.h>
#include <hip/hip_bf16.h>
#include <math.h>

#define D 256
#define NCAM 500
#define NPT 100000
#define SCAN_NB ((NPT + 1023) / 1024)   // 98 blocks of 1024

typedef __attribute__((ext_vector_type(8))) short bf16x8;
typedef __attribute__((ext_vector_type(4))) float f32x4;

// round-to-nearest-even fp32 -> bf16 (raw ushort)
__device__ __forceinline__ unsigned short f2bf(float f) {
    unsigned u = __float_as_uint(f);
    u += 0x7FFFu + ((u >> 16) & 1u);
    return (unsigned short)(u >> 16);
}
__device__ __forceinline__ float bf2f(unsigned short h) {
    return __uint_as_float((unsigned)h << 16);
}

// ---------------- histogram of edge -> point / cam --------------------------
__global__ void hist_kernel(const int* __restrict__ ci, const int* __restrict__ pi,
                            int* __restrict__ cnt_pt, int* __restrict__ cnt_cam, int E) {
    int i = blockIdx.x * 256 + threadIdx.x;
    if (i < E) {
        atomicAdd(&cnt_pt[pi[i]], 1);
        atomicAdd(&cnt_cam[ci[i]], 1);
    }
}

// ---------------- parallel scan, phase A: per-block reduce ------------------
__global__ __launch_bounds__(1024) void scan_partA(const int* __restrict__ cnt_pt,
                                                   int* __restrict__ blk_sum) {
    __shared__ int lds[1024];
    int t = threadIdx.x;
    int i = blockIdx.x * 1024 + t;
    lds[t] = (i < NPT) ? cnt_pt[i] : 0;
    __syncthreads();
    for (int s = 512; s > 0; s >>= 1) {
        if (t < s) lds[t] += lds[t + s];
        __syncthreads();
    }
    if (t == 0) blk_sum[blockIdx.x] = lds[0];
}

// ---------------- phase B: scan 98 block sums + 500 cam counts (1 block) ----
__global__ __launch_bounds__(512) void scan_partB(const int* __restrict__ blk_sum,
                                                  int* __restrict__ blk_base,
                                                  int* __restrict__ off_pt,
                                                  const int* __restrict__ cnt_cam,
                                                  int* __restrict__ off_cam,
                                                  int* __restrict__ cur_cam) {
    __shared__ int lds[512];
    int t = threadIdx.x;
    lds[t] = (t < SCAN_NB) ? blk_sum[t] : 0;
    __syncthreads();
    for (int off = 1; off < 512; off <<= 1) {
        int v = (t >= off) ? lds[t - off] : 0;
        __syncthreads();
        lds[t] += v;
        __syncthreads();
    }
    if (t < SCAN_NB) blk_base[t] = (t == 0) ? 0 : lds[t - 1];
    if (t == SCAN_NB) off_pt[NPT] = lds[SCAN_NB - 1];   // total = E
    __syncthreads();
    // cams
    lds[t] = (t < NCAM) ? cnt_cam[t] : 0;
    __syncthreads();
    for (int off = 1; off < 512; off <<= 1) {
        int v = (t >= off) ? lds[t - off] : 0;
        __syncthreads();
        lds[t] += v;
        __syncthreads();
    }
    if (t < NCAM) {
        int ex = (t == 0) ? 0 : lds[t - 1];
        off_cam[t] = ex;
        cur_cam[t] = ex;
    }
    if (t == NCAM) off_cam[NCAM] = lds[NCAM - 1];
}

// ---------------- phase C: per-block local scan + base ----------------------
__global__ __launch_bounds__(1024) void scan_partC(const int* __restrict__ cnt_pt,
                                                   const int* __restrict__ blk_base,
                                                   int* __restrict__ off_pt,
                                                   int* __restrict__ cur_pt) {
    __shared__ int lds[1024];
    int t = threadIdx.x;
    int i = blockIdx.x * 1024 + t;
    lds[t] = (i < NPT) ? cnt_pt[i] : 0;
    __syncthreads();
    for (int off = 1; off < 1024; off <<= 1) {
        int v = (t >= off) ? lds[t - off] : 0;
        __syncthreads();
        lds[t] += v;
        __syncthreads();
    }
    if (i < NPT) {
        int ex = blk_base[blockIdx.x] + ((t == 0) ? 0 : lds[t - 1]);
        off_pt[i] = ex;
        cur_pt[i] = ex;
    }
}

// ---------------- bucket: edge ids grouped by point and by cam --------------
__global__ void bucket_kernel(const int* __restrict__ ci, const int* __restrict__ pi,
                              int* __restrict__ cur_pt, int* __restrict__ cur_cam,
                              int* __restrict__ order_pt, int* __restrict__ order_cam,
                              int E) {
    int i = blockIdx.x * 256 + threadIdx.x;
    if (i < E) {
        int pos = atomicAdd(&cur_pt[pi[i]], 1);
        order_pt[pos] = i;
        int pos2 = atomicAdd(&cur_cam[ci[i]], 1);
        order_cam[pos2] = i;
    }
}

// ---------------- point aggregation by gather (1 wave/point, float4/lane),
// writes split-bf16 A (hi/lo) for the MFMA GEMM, fused apt dot --------------
__global__ void pt_agg_kernel(const float* __restrict__ ef,
                              const int* __restrict__ order_pt,
                              const int* __restrict__ off_pt,
                              const float* __restrict__ vpt,
                              unsigned short* __restrict__ Ahi,
                              unsigned short* __restrict__ Alo,
                              float* __restrict__ apt) {
    int wave = threadIdx.x >> 6;
    int lane = threadIdx.x & 63;
    int p = blockIdx.x * 4 + wave;
    if (p >= NPT) return;
    int j0 = off_pt[p], j1 = off_pt[p + 1];
    float4 acc = make_float4(0.f, 0.f, 0.f, 0.f);
    for (int j = j0; j < j1; j++) {
        int e = order_pt[j];
        float4 v = *(const float4*)(ef + (size_t)e * D + lane * 4);
        acc.x += v.x; acc.y += v.y; acc.z += v.z; acc.w += v.w;
    }
    // split-bf16 store: hi = bf16(x), lo = bf16(x - hi)
    ushort4 h, l;
    h.x = f2bf(acc.x); l.x = f2bf(acc.x - bf2f(h.x));
    h.y = f2bf(acc.y); l.y = f2bf(acc.y - bf2f(h.y));
    h.z = f2bf(acc.z); l.z = f2bf(acc.z - bf2f(h.z));
    h.w = f2bf(acc.w); l.w = f2bf(acc.w - bf2f(h.w));
    *(ushort4*)(Ahi + (size_t)p * D + lane * 4) = h;
    *(ushort4*)(Alo + (size_t)p * D + lane * 4) = l;
    float4 vv = *(const float4*)(vpt + lane * 4);
    float d = acc.x * vv.x + acc.y * vv.y + acc.z * vv.z + acc.w * vv.w;
    for (int off = 32; off > 0; off >>= 1) d += __shfl_down(d, off);
    if (lane == 0) apt[p] = d;
}

// ---------------- cam aggregation by gather (500 x 8 blocks, thread=feature)
__global__ void cam_agg_kernel(const float* __restrict__ ef,
                               const int* __restrict__ order_cam,
                               const int* __restrict__ off_cam,
                               float* __restrict__ cam_agg) {
    int c = blockIdx.x;
    int q = blockIdx.y;      // 0..7 slice of this cam's edge list
    int t = threadIdx.x;     // feature
    int j0 = off_cam[c], j1 = off_cam[c + 1];
    float acc = 0.f;
    for (int j = j0 + q; j < j1; j += 8) {
        int e = order_cam[j];
        acc += ef[(size_t)e * D + t];
    }
    atomicAdd(&cam_agg[(size_t)c * D + t], acc);
}

// ---------------- fold weights; Cpt emitted as split-bf16 -------------------
__global__ void combine_weights(const float* __restrict__ Wcam,
                                const float* __restrict__ Wpt,
                                const float* __restrict__ Wattn,
                                const float* __restrict__ Wfin,
                                float* __restrict__ CcamT,
                                unsigned short* __restrict__ Bhi,
                                unsigned short* __restrict__ Blo,
                                float* __restrict__ vcam,
                                float* __restrict__ vpt) {
    int b = blockIdx.x;
    int i = threadIdx.x;
    if (b < 256) {
        int o = b;
        float acc = 0.f;
        for (int j = 0; j < 256; j++) acc += Wfin[o * 512 + j] * Wcam[j * 256 + i];
        CcamT[i * 256 + o] = acc;
    } else if (b < 512) {
        int o = b - 256;
        float acc = 0.f;
        for (int j = 0; j < 256; j++) acc += Wfin[o * 512 + 256 + j] * Wpt[j * 256 + i];
        unsigned short h = f2bf(acc);
        Bhi[o * 256 + i] = h;
        Blo[o * 256 + i] = f2bf(acc - bf2f(h));
    } else if (b == 512) {
        float acc = 0.f;
        for (int j = 0; j < 256; j++) acc += Wattn[j] * Wcam[j * 256 + i];
        vcam[i] = acc;
    } else {
        float acc = 0.f;
        for (int j = 0; j < 256; j++) acc += Wattn[256 + j] * Wpt[j * 256 + i];
        vpt[i] = acc;
    }
}

// ---------------- cam projection (unchanged, tiny) --------------------------
__global__ void cam_proj(const float* __restrict__ cam_agg,
                         const float* __restrict__ CcamT,
                         const float* __restrict__ vcam,
                         float* __restrict__ gcam,
                         float* __restrict__ acam) {
    __shared__ float row[256];
    __shared__ float red[256];
    int c = blockIdx.x;
    int t = threadIdx.x;
    row[t] = cam_agg[(size_t)c * 256 + t];
    __syncthreads();
    float acc = 0.f;
    for (int i = 0; i < 256; i++) acc += row[i] * CcamT[i * 256 + t];
    gcam[(size_t)c * 256 + t] = acc;
    red[t] = row[t] * vcam[t];
    __syncthreads();
    for (int s = 128; s > 0; s >>= 1) {
        if (t < s) red[t] += red[t + s];
        __syncthreads();
    }
    if (t == 0) acam[c] = red[0];
}

// ---------------- main GEMM: split-bf16 MFMA, no LDS ------------------------
// gpt[m, o] = sum_i A[m,i] * B[o,i];  A = Ahi+Alo, B = Bhi+Blo (bf16 splits)
// mfma_f32_16x16x32_bf16 layouts:
//   A frag: row = lane&15, k = (lane>>4)*8 + j  (8 contiguous bf16 / lane)
//   B frag: col = lane&15, k = (lane>>4)*8 + j
//   D frag: col = lane&15, row = (lane>>4)*4 + reg   [verified m89]
__global__ __launch_bounds__(256) void gemm_mfma(const unsigned short* __restrict__ Ahi,
                                                 const unsigned short* __restrict__ Alo,
                                                 const unsigned short* __restrict__ Bhi,
                                                 const unsigned short* __restrict__ Blo,
                                                 float* __restrict__ Cout, int M) {
    int wave = threadIdx.x >> 6;
    int lane = threadIdx.x & 63;
    int m0 = blockIdx.x * 64;        // 64 rows per block (4 waves share A rows)
    int n0 = wave * 64;              // each wave owns a 64-col slice of N=256
    int fr = lane & 15;
    int kg = (lane >> 4) * 8;
    f32x4 acc[4][4] = {};
    // clamp A fragment rows to valid range (stores for rows >= M are masked anyway)
    size_t ar[4];
#pragma unroll
    for (int f = 0; f < 4; f++) {
        int row = m0 + f * 16 + fr;
        if (row >= M) row = M - 1;
        ar[f] = (size_t)row * 256 + kg;
    }
    size_t brow = (size_t)(n0 + fr) * 256 + kg;
    for (int k0 = 0; k0 < 256; k0 += 32) {
        bf16x8 ah[4], al[4], bh[4], bl[4];
#pragma unroll
        for (int f = 0; f < 4; f++) {
            ah[f] = *(const bf16x8*)(Ahi + ar[f] + k0);
            al[f] = *(const bf16x8*)(Alo + ar[f] + k0);
            bh[f] = *(const bf16x8*)(Bhi + brow + (size_t)f * 16 * 256 + k0);
            bl[f] = *(const bf16x8*)(Blo + brow + (size_t)f * 16 * 256 + k0);
        }
#pragma unroll
        for (int mf = 0; mf < 4; mf++) {
#pragma unroll
            for (int nf = 0; nf < 4; nf++) {
                acc[mf][nf] = __builtin_amdgcn_mfma_f32_16x16x32_bf16(ah[mf], bh[nf], acc[mf][nf], 0, 0, 0);
                acc[mf][nf] = __builtin_amdgcn_mfma_f32_16x16x32_bf16(ah[mf], bl[nf], acc[mf][nf], 0, 0, 0);
                acc[mf][nf] = __builtin_amdgcn_mfma_f32_16x16x32_bf16(al[mf], bh[nf], acc[mf][nf], 0, 0, 0);
            }
        }
    }
    int rbase = (lane >> 4) * 4;
#pragma unroll
    for (int mf = 0; mf < 4; mf++) {
#pragma unroll
        for (int r = 0; r < 4; r++) {
            int row = m0 + mf * 16 + rbase + r;
            if (row < M) {
#pragma unroll
                for (int nf = 0; nf < 4; nf++)
                    Cout[(size_t)row * 256 + n0 + nf * 16 + fr] = acc[mf][nf][r];
            }
        }
    }
}

// ---------------- e + global max (monotonic-uint atomicMax) -----------------
__device__ __forceinline__ unsigned float_key(float f) {
    unsigned b = __float_as_uint(f);
    return (b & 0x80000000u) ? ~b : (b | 0x80000000u);
}
__device__ __forceinline__ float key_float(unsigned k) {
    return __uint_as_float((k & 0x80000000u) ? (k & 0x7FFFFFFFu) : ~k);
}

__global__ void e_max_kernel(const int* __restrict__ ci, const int* __restrict__ pi,
                             const float* __restrict__ acam, const float* __restrict__ apt,
                             float* __restrict__ ebuf, unsigned* __restrict__ maxkey, int E) {
    int i = blockIdx.x * 256 + threadIdx.x;
    float e = -INFINITY;
    if (i < E) {
        e = acam[ci[i]] + apt[pi[i]];
        ebuf[i] = e;
    }
    __shared__ float red[256];
    int t = threadIdx.x;
    red[t] = e;
    __syncthreads();
    for (int s = 128; s > 0; s >>= 1) {
        if (t < s) red[t] = fmaxf(red[t], red[t + s]);
        __syncthreads();
    }
    if (t == 0) atomicMax(maxkey, float_key(red[0]));
}

__global__ void sumexp_kernel(float* __restrict__ ebuf,
                              const unsigned* __restrict__ maxkey,
                              float* __restrict__ sumexp, int E) {
    int i = blockIdx.x * 256 + threadIdx.x;
    float mx = key_float(*maxkey);
    float p = 0.f;
    if (i < E) {
        p = expf(ebuf[i] - mx);
        ebuf[i] = p;
    }
    __shared__ float red[256];
    int t = threadIdx.x;
    red[t] = p;
    __syncthreads();
    for (int s = 128; s > 0; s >>= 1) {
        if (t < s) red[t] += red[t + s];
        __syncthreads();
    }
    if (t == 0) atomicAdd(sumexp, red[0]);
}

// ---------------- output: wave-per-edge, grid-stride, float4 ----------------
__global__ __launch_bounds__(256) void out_kernel(const int* __restrict__ ci, const int* __restrict__ pi,
                           const float* __restrict__ gcam, const float* __restrict__ gpt,
                           const float* __restrict__ bfin, const float* __restrict__ ebuf,
                           const float* __restrict__ sumexp, float* __restrict__ out, int E) {
    int lane = threadIdx.x & 63;
    int wid = (blockIdx.x * 256 + threadIdx.x) >> 6;
    int nw = (gridDim.x * 256) >> 6;
    float inv = 1.0f / (*sumexp);
    float4 bb = *(const float4*)(bfin + lane * 4);
    for (int e = wid; e < E; e += nw) {
        float scale = ebuf[e] * inv;
        int c = ci[e];
        int p = pi[e];
        float4 gc = *(const float4*)(gcam + (size_t)c * 256 + lane * 4);
        float4 gp = *(const float4*)(gpt + (size_t)p * 256 + lane * 4);
        float4 v;
        v.x = fmaxf((gc.x + gp.x + bb.x) * scale, 0.f);
        v.y = fmaxf((gc.y + gp.y + bb.y) * scale, 0.f);
        v.z = fmaxf((gc.z + gp.z + bb.z) * scale, 0.f);
        v.w = fmaxf((gc.w + gp.w + bb.w) * scale, 0.f);
        *(float4*)(out + (size_t)e * 256 + lane * 4) = v;
    }
}

extern "C" void kernel_launch(void* const* d_in, const int* in_sizes, int n_in,
                              void* d_out, int out_size, void* d_ws, size_t ws_size,
                              hipStream_t stream) {
    const float* ef    = (const float*)d_in[0];
    const int*   ci    = (const int*)d_in[1];
    const int*   pi    = (const int*)d_in[2];
    const float* Wcam  = (const float*)d_in[5];
    const float* Wpt   = (const float*)d_in[6];
    const float* Wattn = (const float*)d_in[7];
    const float* Wfin  = (const float*)d_in[8];
    const float* bfin  = (const float*)d_in[9];
    float* out = (float*)d_out;
    int E = in_sizes[0] / D;

    float* ws = (float*)d_ws;
    float* cam_agg = ws;                              // 128000 floats
    float* aregion = cam_agg + (size_t)NCAM * D;      // 25,600,000 floats (A hi/lo splits)
    unsigned short* Ahi = (unsigned short*)aregion;            // NPT*256 ushorts
    unsigned short* Alo = Ahi + (size_t)NPT * D;               // NPT*256 ushorts (same region)
    float* CcamT   = aregion + (size_t)NPT * D;       // 65536
    float* bregion = CcamT + 65536;                   // 65536 floats (B hi/lo splits)
    unsigned short* Bhi = (unsigned short*)bregion;            // 65536 ushorts
    unsigned short* Blo = Bhi + 65536;                         // 65536 ushorts
    float* vcam    = bregion + 65536;                 // 256
    float* vpt     = vcam + 256;                      // 256
    float* gcam    = vpt + 256;                       // 128000
    float* acam    = gcam + (size_t)NCAM * D;         // 512 (padded)
    float* gpt     = acam + 512;                      // 25,600,000
    float* apt     = gpt + (size_t)NPT * D;           // 100000
    float* ebuf    = apt + NPT;                       // E
    unsigned* maxkey = (unsigned*)(ebuf + E);
    float* sumexp  = (float*)(maxkey + 1);

    // counting-sort metadata overlaid on gpt (all consumed before gemm writes gpt)
    int* ib        = (int*)gpt;
    int* cnt_pt    = ib;                      // NPT
    int* cnt_cam   = cnt_pt + NPT;            // NCAM
    int* off_pt    = cnt_cam + NCAM;          // NPT+1
    int* off_cam   = off_pt + NPT + 1;        // NCAM+1
    int* cur_pt    = off_cam + NCAM + 1;      // NPT
    int* cur_cam   = cur_pt + NPT;            // NCAM
    int* order_pt  = cur_cam + NCAM;          // E
    int* order_cam = order_pt + E;            // E
    int* blk_sum   = order_cam + E;           // SCAN_NB
    int* blk_base  = blk_sum + SCAN_NB;       // SCAN_NB

    hipMemsetAsync(cam_agg, 0, (size_t)NCAM * D * sizeof(float), stream);
    hipMemsetAsync(maxkey, 0, 2 * sizeof(unsigned), stream);
    hipMemsetAsync(cnt_pt, 0, (size_t)(NPT + NCAM) * sizeof(int), stream);

    int eb = (E + 255) / 256;
    hist_kernel<<<eb, 256, 0, stream>>>(ci, pi, cnt_pt, cnt_cam, E);
    combine_weights<<<514, 256, 0, stream>>>(Wcam, Wpt, Wattn, Wfin, CcamT, Bhi, Blo, vcam, vpt);
    scan_partA<<<SCAN_NB, 1024, 0, stream>>>(cnt_pt, blk_sum);
    scan_partB<<<1, 512, 0, stream>>>(blk_sum, blk_base, off_pt, cnt_cam, off_cam, cur_cam);
    scan_partC<<<SCAN_NB, 1024, 0, stream>>>(cnt_pt, blk_base, off_pt, cur_pt);
    bucket_kernel<<<eb, 256, 0, stream>>>(ci, pi, cur_pt, cur_cam, order_pt, order_cam, E);
    pt_agg_kernel<<<(NPT + 3) / 4, 256, 0, stream>>>(ef, order_pt, off_pt, vpt, Ahi, Alo, apt);
    cam_agg_kernel<<<dim3(NCAM, 8), 256, 0, stream>>>(ef, order_cam, off_cam, cam_agg);
    cam_proj<<<NCAM, 256, 0, stream>>>(cam_agg, CcamT, vcam, gcam, acam);
    gemm_mfma<<<(NPT + 63) / 64, 256, 0, stream>>>(Ahi, Alo, Bhi, Blo, gpt, NPT);
    e_max_kernel<<<eb, 256, 0, stream>>>(ci, pi, acam, apt, ebuf, maxkey, E);
    sumexp_kernel<<<eb, 256, 0, stream>>>(ebuf, maxkey, sumexp, E);
    out_kernel<<<2048, 256, 0, stream>>>(ci, pi, gcam, gpt, bfin, ebuf, sumexp, out, E);
}

// Round 6
// 979.964 us; speedup vs baseline: 1.3559x; 1.0033x over previous
//
#include <hip/hip_runtime.h>
#include <hip/hip_bf16.h>
#include <math.h>

#define D 256
#define NCAM 500
#define NPT 100000
#define SCAN_NB ((NPT + 1023) / 1024)   // 98 blocks of 1024

typedef __attribute__((ext_vector_type(8))) short bf16x8;
typedef __attribute__((ext_vector_type(4))) float f32x4;

// round-to-nearest-even fp32 -> bf16 (raw ushort)
__device__ __forceinline__ unsigned short f2bf(float f) {
    unsigned u = __float_as_uint(f);
    u += 0x7FFFu + ((u >> 16) & 1u);
    return (unsigned short)(u >> 16);
}
__device__ __forceinline__ float bf2f(unsigned short h) {
    return __uint_as_float((unsigned)h << 16);
}

// ---------------- histogram of edge -> point / cam --------------------------
__global__ void hist_kernel(const int* __restrict__ ci, const int* __restrict__ pi,
                            int* __restrict__ cnt_pt, int* __restrict__ cnt_cam, int E) {
    int i = blockIdx.x * 256 + threadIdx.x;
    if (i < E) {
        atomicAdd(&cnt_pt[pi[i]], 1);
        atomicAdd(&cnt_cam[ci[i]], 1);
    }
}

// ---------------- parallel scan, phase A: per-block reduce ------------------
__global__ __launch_bounds__(1024) void scan_partA(const int* __restrict__ cnt_pt,
                                                   int* __restrict__ blk_sum) {
    __shared__ int lds[1024];
    int t = threadIdx.x;
    int i = blockIdx.x * 1024 + t;
    lds[t] = (i < NPT) ? cnt_pt[i] : 0;
    __syncthreads();
    for (int s = 512; s > 0; s >>= 1) {
        if (t < s) lds[t] += lds[t + s];
        __syncthreads();
    }
    if (t == 0) blk_sum[blockIdx.x] = lds[0];
}

// ---------------- phase B: scan 98 block sums + 500 cam counts (1 block) ----
__global__ __launch_bounds__(512) void scan_partB(const int* __restrict__ blk_sum,
                                                  int* __restrict__ blk_base,
                                                  int* __restrict__ off_pt,
                                                  const int* __restrict__ cnt_cam,
                                                  int* __restrict__ off_cam,
                                                  int* __restrict__ cur_cam) {
    __shared__ int lds[512];
    int t = threadIdx.x;
    lds[t] = (t < SCAN_NB) ? blk_sum[t] : 0;
    __syncthreads();
    for (int off = 1; off < 512; off <<= 1) {
        int v = (t >= off) ? lds[t - off] : 0;
        __syncthreads();
        lds[t] += v;
        __syncthreads();
    }
    if (t < SCAN_NB) blk_base[t] = (t == 0) ? 0 : lds[t - 1];
    if (t == SCAN_NB) off_pt[NPT] = lds[SCAN_NB - 1];   // total = E
    __syncthreads();
    // cams
    lds[t] = (t < NCAM) ? cnt_cam[t] : 0;
    __syncthreads();
    for (int off = 1; off < 512; off <<= 1) {
        int v = (t >= off) ? lds[t - off] : 0;
        __syncthreads();
        lds[t] += v;
        __syncthreads();
    }
    if (t < NCAM) {
        int ex = (t == 0) ? 0 : lds[t - 1];
        off_cam[t] = ex;
        cur_cam[t] = ex;
    }
    if (t == NCAM) off_cam[NCAM] = lds[NCAM - 1];
}

// ---------------- phase C: per-block local scan + base ----------------------
__global__ __launch_bounds__(1024) void scan_partC(const int* __restrict__ cnt_pt,
                                                   const int* __restrict__ blk_base,
                                                   int* __restrict__ off_pt,
                                                   int* __restrict__ cur_pt) {
    __shared__ int lds[1024];
    int t = threadIdx.x;
    int i = blockIdx.x * 1024 + t;
    lds[t] = (i < NPT) ? cnt_pt[i] : 0;
    __syncthreads();
    for (int off = 1; off < 1024; off <<= 1) {
        int v = (t >= off) ? lds[t - off] : 0;
        __syncthreads();
        lds[t] += v;
        __syncthreads();
    }
    if (i < NPT) {
        int ex = blk_base[blockIdx.x] + ((t == 0) ? 0 : lds[t - 1]);
        off_pt[i] = ex;
        cur_pt[i] = ex;
    }
}

// ---------------- bucket: edge ids grouped by point and by cam --------------
__global__ void bucket_kernel(const int* __restrict__ ci, const int* __restrict__ pi,
                              int* __restrict__ cur_pt, int* __restrict__ cur_cam,
                              int* __restrict__ order_pt, int* __restrict__ order_cam,
                              int E) {
    int i = blockIdx.x * 256 + threadIdx.x;
    if (i < E) {
        int pos = atomicAdd(&cur_pt[pi[i]], 1);
        order_pt[pos] = i;
        int pos2 = atomicAdd(&cur_cam[ci[i]], 1);
        order_cam[pos2] = i;
    }
}

// ---------------- point aggregation by gather (1 wave/point, float4/lane),
// writes split-bf16 A (hi/lo) for the MFMA GEMM, fused apt dot --------------
__global__ void pt_agg_kernel(const float* __restrict__ ef,
                              const int* __restrict__ order_pt,
                              const int* __restrict__ off_pt,
                              const float* __restrict__ vpt,
                              unsigned short* __restrict__ Ahi,
                              unsigned short* __restrict__ Alo,
                              float* __restrict__ apt) {
    int wave = threadIdx.x >> 6;
    int lane = threadIdx.x & 63;
    int p = blockIdx.x * 4 + wave;
    if (p >= NPT) return;
    int j0 = off_pt[p], j1 = off_pt[p + 1];
    float4 acc = make_float4(0.f, 0.f, 0.f, 0.f);
    for (int j = j0; j < j1; j++) {
        int e = order_pt[j];
        float4 v = *(const float4*)(ef + (size_t)e * D + lane * 4);
        acc.x += v.x; acc.y += v.y; acc.z += v.z; acc.w += v.w;
    }
    // split-bf16 store: hi = bf16(x), lo = bf16(x - hi)
    ushort4 h, l;
    h.x = f2bf(acc.x); l.x = f2bf(acc.x - bf2f(h.x));
    h.y = f2bf(acc.y); l.y = f2bf(acc.y - bf2f(h.y));
    h.z = f2bf(acc.z); l.z = f2bf(acc.z - bf2f(h.z));
    h.w = f2bf(acc.w); l.w = f2bf(acc.w - bf2f(h.w));
    *(ushort4*)(Ahi + (size_t)p * D + lane * 4) = h;
    *(ushort4*)(Alo + (size_t)p * D + lane * 4) = l;
    float4 vv = *(const float4*)(vpt + lane * 4);
    float d = acc.x * vv.x + acc.y * vv.y + acc.z * vv.z + acc.w * vv.w;
    for (int off = 32; off > 0; off >>= 1) d += __shfl_down(d, off);
    if (lane == 0) apt[p] = d;
}

// ---------------- cam aggregation by gather (500 x 8 blocks, thread=feature)
__global__ void cam_agg_kernel(const float* __restrict__ ef,
                               const int* __restrict__ order_cam,
                               const int* __restrict__ off_cam,
                               float* __restrict__ cam_agg) {
    int c = blockIdx.x;
    int q = blockIdx.y;      // 0..7 slice of this cam's edge list
    int t = threadIdx.x;     // feature
    int j0 = off_cam[c], j1 = off_cam[c + 1];
    float acc = 0.f;
    for (int j = j0 + q; j < j1; j += 8) {
        int e = order_cam[j];
        acc += ef[(size_t)e * D + t];
    }
    atomicAdd(&cam_agg[(size_t)c * D + t], acc);
}

// ---------------- fold weights; Cpt emitted as split-bf16 -------------------
__global__ void combine_weights(const float* __restrict__ Wcam,
                                const float* __restrict__ Wpt,
                                const float* __restrict__ Wattn,
                                const float* __restrict__ Wfin,
                                float* __restrict__ CcamT,
                                unsigned short* __restrict__ Bhi,
                                unsigned short* __restrict__ Blo,
                                float* __restrict__ vcam,
                                float* __restrict__ vpt) {
    int b = blockIdx.x;
    int i = threadIdx.x;
    if (b < 256) {
        int o = b;
        float acc = 0.f;
        for (int j = 0; j < 256; j++) acc += Wfin[o * 512 + j] * Wcam[j * 256 + i];
        CcamT[i * 256 + o] = acc;
    } else if (b < 512) {
        int o = b - 256;
        float acc = 0.f;
        for (int j = 0; j < 256; j++) acc += Wfin[o * 512 + 256 + j] * Wpt[j * 256 + i];
        unsigned short h = f2bf(acc);
        Bhi[o * 256 + i] = h;
        Blo[o * 256 + i] = f2bf(acc - bf2f(h));
    } else if (b == 512) {
        float acc = 0.f;
        for (int j = 0; j < 256; j++) acc += Wattn[j] * Wcam[j * 256 + i];
        vcam[i] = acc;
    } else {
        float acc = 0.f;
        for (int j = 0; j < 256; j++) acc += Wattn[256 + j] * Wpt[j * 256 + i];
        vpt[i] = acc;
    }
}

// ---------------- cam projection (unchanged, tiny) --------------------------
__global__ void cam_proj(const float* __restrict__ cam_agg,
                         const float* __restrict__ CcamT,
                         const float* __restrict__ vcam,
                         float* __restrict__ gcam,
                         float* __restrict__ acam) {
    __shared__ float row[256];
    __shared__ float red[256];
    int c = blockIdx.x;
    int t = threadIdx.x;
    row[t] = cam_agg[(size_t)c * 256 + t];
    __syncthreads();
    float acc = 0.f;
    for (int i = 0; i < 256; i++) acc += row[i] * CcamT[i * 256 + t];
    gcam[(size_t)c * 256 + t] = acc;
    red[t] = row[t] * vcam[t];
    __syncthreads();
    for (int s = 128; s > 0; s >>= 1) {
        if (t < s) red[t] += red[t + s];
        __syncthreads();
    }
    if (t == 0) acam[c] = red[0];
}

// ---------------- e + per-block softmax partials (fused max & sumexp) -------
__global__ void e_kernel(const int* __restrict__ ci, const int* __restrict__ pi,
                         const float* __restrict__ acam, const float* __restrict__ apt,
                         float* __restrict__ ebuf, float* __restrict__ bmax,
                         float* __restrict__ bsum, int E) {
    int i = blockIdx.x * 256 + threadIdx.x;
    int t = threadIdx.x;
    float e = -INFINITY;
    if (i < E) {
        e = acam[ci[i]] + apt[pi[i]];
        ebuf[i] = e;
    }
    __shared__ float red[256];
    red[t] = e;
    __syncthreads();
    for (int s = 128; s > 0; s >>= 1) {
        if (t < s) red[t] = fmaxf(red[t], red[t + s]);
        __syncthreads();
    }
    float bm = red[0];
    __syncthreads();
    float p = (i < E) ? __expf(e - bm) : 0.f;
    red[t] = p;
    __syncthreads();
    for (int s = 128; s > 0; s >>= 1) {
        if (t < s) red[t] += red[t + s];
        __syncthreads();
    }
    if (t == 0) {
        bmax[blockIdx.x] = bm;
        bsum[blockIdx.x] = red[0];
    }
}

// ---------------- combine block partials -> (gmax, 1/gsum) ------------------
__global__ __launch_bounds__(1024) void softmax_combine(const float* __restrict__ bmax,
                                                        const float* __restrict__ bsum,
                                                        float* __restrict__ gsm, int nb) {
    __shared__ float rmax[1024];
    __shared__ float rsum[1024];
    int t = threadIdx.x;
    float m = -INFINITY;
    for (int i = t; i < nb; i += 1024) m = fmaxf(m, bmax[i]);
    rmax[t] = m;
    __syncthreads();
    for (int s = 512; s > 0; s >>= 1) {
        if (t < s) rmax[t] = fmaxf(rmax[t], rmax[t + s]);
        __syncthreads();
    }
    float gm = rmax[0];
    __syncthreads();
    float s = 0.f;
    for (int i = t; i < nb; i += 1024) s += bsum[i] * __expf(bmax[i] - gm);
    rsum[t] = s;
    __syncthreads();
    for (int st = 512; st > 0; st >>= 1) {
        if (t < st) rsum[t] += rsum[t + st];
        __syncthreads();
    }
    if (t == 0) {
        gsm[0] = gm;
        gsm[1] = 1.0f / rsum[0];
    }
}

// ---------------- fused GEMM + output: split-bf16 MFMA, LDS tile epilogue ---
// h_pt tile (64 points x 256) computed in AGPRs -> LDS; then the block's
// contiguous edge slice [off_pt[m0], off_pt[m0+64]) is written directly:
// out[e] = relu((tile[pi[e]-m0] + gcam[ci[e]] + b) * exp(ebuf[e]-gmax)*ginv)
__global__ __launch_bounds__(256) void gemm_out(const unsigned short* __restrict__ Ahi,
                                                const unsigned short* __restrict__ Alo,
                                                const unsigned short* __restrict__ Bhi,
                                                const unsigned short* __restrict__ Blo,
                                                const int* __restrict__ order_pt,
                                                const int* __restrict__ off_pt,
                                                const int* __restrict__ ci,
                                                const int* __restrict__ pi,
                                                const float* __restrict__ ebuf,
                                                const float* __restrict__ gsm,
                                                const float* __restrict__ gcam,
                                                const float* __restrict__ bfin,
                                                float* __restrict__ out, int M) {
    __shared__ float tile[64][256];   // 64 KB
    int wave = threadIdx.x >> 6;
    int lane = threadIdx.x & 63;
    int m0 = blockIdx.x * 64;        // 64 points per block
    int n0 = wave * 64;              // each wave owns a 64-col slice of N=256
    int fr = lane & 15;
    int kg = (lane >> 4) * 8;
    f32x4 acc[4][4] = {};
    // clamp A fragment rows to valid range (rows >= M are never consumed)
    size_t ar[4];
#pragma unroll
    for (int f = 0; f < 4; f++) {
        int row = m0 + f * 16 + fr;
        if (row >= M) row = M - 1;
        ar[f] = (size_t)row * 256 + kg;
    }
    size_t brow = (size_t)(n0 + fr) * 256 + kg;
    for (int k0 = 0; k0 < 256; k0 += 32) {
        bf16x8 ah[4], al[4], bh[4], bl[4];
#pragma unroll
        for (int f = 0; f < 4; f++) {
            ah[f] = *(const bf16x8*)(Ahi + ar[f] + k0);
            al[f] = *(const bf16x8*)(Alo + ar[f] + k0);
            bh[f] = *(const bf16x8*)(Bhi + brow + (size_t)f * 16 * 256 + k0);
            bl[f] = *(const bf16x8*)(Blo + brow + (size_t)f * 16 * 256 + k0);
        }
#pragma unroll
        for (int mf = 0; mf < 4; mf++) {
#pragma unroll
            for (int nf = 0; nf < 4; nf++) {
                acc[mf][nf] = __builtin_amdgcn_mfma_f32_16x16x32_bf16(ah[mf], bh[nf], acc[mf][nf], 0, 0, 0);
                acc[mf][nf] = __builtin_amdgcn_mfma_f32_16x16x32_bf16(ah[mf], bl[nf], acc[mf][nf], 0, 0, 0);
                acc[mf][nf] = __builtin_amdgcn_mfma_f32_16x16x32_bf16(al[mf], bh[nf], acc[mf][nf], 0, 0, 0);
            }
        }
    }
    // spill accumulators to LDS tile
    int rbase = (lane >> 4) * 4;
#pragma unroll
    for (int mf = 0; mf < 4; mf++) {
#pragma unroll
        for (int r = 0; r < 4; r++) {
#pragma unroll
            for (int nf = 0; nf < 4; nf++)
                tile[mf * 16 + rbase + r][n0 + nf * 16 + fr] = acc[mf][nf][r];
        }
    }
    __syncthreads();
    // edge epilogue: waves split the block's contiguous edge slice
    float gmax = gsm[0];
    float ginv = gsm[1];
    int hi = m0 + 64; if (hi > M) hi = M;
    int j0 = off_pt[m0];
    int j1 = off_pt[hi];
    float4 bb = *(const float4*)(bfin + lane * 4);
    for (int j = j0 + wave; j < j1; j += 4) {
        int e = order_pt[j];
        int lp = pi[e] - m0;
        int c = ci[e];
        float scale = __expf(ebuf[e] - gmax) * ginv;
        float4 tv = *(const float4*)&tile[lp][lane * 4];
        float4 gc = *(const float4*)(gcam + (size_t)c * 256 + lane * 4);
        float4 v;
        v.x = fmaxf((tv.x + gc.x + bb.x) * scale, 0.f);
        v.y = fmaxf((tv.y + gc.y + bb.y) * scale, 0.f);
        v.z = fmaxf((tv.z + gc.z + bb.z) * scale, 0.f);
        v.w = fmaxf((tv.w + gc.w + bb.w) * scale, 0.f);
        *(float4*)(out + (size_t)e * 256 + lane * 4) = v;
    }
}

extern "C" void kernel_launch(void* const* d_in, const int* in_sizes, int n_in,
                              void* d_out, int out_size, void* d_ws, size_t ws_size,
                              hipStream_t stream) {
    const float* ef    = (const float*)d_in[0];
    const int*   ci    = (const int*)d_in[1];
    const int*   pi    = (const int*)d_in[2];
    const float* Wcam  = (const float*)d_in[5];
    const float* Wpt   = (const float*)d_in[6];
    const float* Wattn = (const float*)d_in[7];
    const float* Wfin  = (const float*)d_in[8];
    const float* bfin  = (const float*)d_in[9];
    float* out = (float*)d_out;
    int E = in_sizes[0] / D;
    int eb = (E + 255) / 256;   // softmax partial blocks

    float* ws = (float*)d_ws;
    float* cam_agg = ws;                              // 128000 floats
    float* aregion = cam_agg + (size_t)NCAM * D;      // 25,600,000 floats (A hi/lo splits)
    unsigned short* Ahi = (unsigned short*)aregion;            // NPT*256 ushorts
    unsigned short* Alo = Ahi + (size_t)NPT * D;               // NPT*256 ushorts (same region)
    float* CcamT   = aregion + (size_t)NPT * D;       // 65536
    float* bregion = CcamT + 65536;                   // 65536 floats (B hi/lo splits)
    unsigned short* Bhi = (unsigned short*)bregion;            // 65536 ushorts
    unsigned short* Blo = Bhi + 65536;                         // 65536 ushorts
    float* vcam    = bregion + 65536;                 // 256
    float* vpt     = vcam + 256;                      // 256
    float* gcam    = vpt + 256;                       // 128000
    float* acam    = gcam + (size_t)NCAM * D;         // 512 (padded)
    float* apt     = acam + 512;                      // 100000
    float* ebuf    = apt + NPT;                       // E
    float* gsm     = ebuf + E;                        // 2 (gmax, 1/gsum)
    float* bmax    = gsm + 2;                         // eb (<=1024)
    float* bsum    = bmax + 1024;                     // eb

    // counting-sort metadata (dedicated region; persists through gemm_out)
    int* ib        = (int*)(bsum + 1024);
    int* cnt_pt    = ib;                      // NPT
    int* cnt_cam   = cnt_pt + NPT;            // NCAM
    int* off_pt    = cnt_cam + NCAM;          // NPT+1
    int* off_cam   = off_pt + NPT + 1;        // NCAM+1
    int* cur_pt    = off_cam + NCAM + 1;      // NPT
    int* cur_cam   = cur_pt + NPT;            // NCAM
    int* order_pt  = cur_cam + NCAM;          // E
    int* order_cam = order_pt + E;            // E
    int* blk_sum   = order_cam + E;           // SCAN_NB
    int* blk_base  = blk_sum + SCAN_NB;       // SCAN_NB

    hipMemsetAsync(cam_agg, 0, (size_t)NCAM * D * sizeof(float), stream);
    hipMemsetAsync(cnt_pt, 0, (size_t)(NPT + NCAM) * sizeof(int), stream);

    hist_kernel<<<eb, 256, 0, stream>>>(ci, pi, cnt_pt, cnt_cam, E);
    combine_weights<<<514, 256, 0, stream>>>(Wcam, Wpt, Wattn, Wfin, CcamT, Bhi, Blo, vcam, vpt);
    scan_partA<<<SCAN_NB, 1024, 0, stream>>>(cnt_pt, blk_sum);
    scan_partB<<<1, 512, 0, stream>>>(blk_sum, blk_base, off_pt, cnt_cam, off_cam, cur_cam);
    scan_partC<<<SCAN_NB, 1024, 0, stream>>>(cnt_pt, blk_base, off_pt, cur_pt);
    bucket_kernel<<<eb, 256, 0, stream>>>(ci, pi, cur_pt, cur_cam, order_pt, order_cam, E);
    pt_agg_kernel<<<(NPT + 3) / 4, 256, 0, stream>>>(ef, order_pt, off_pt, vpt, Ahi, Alo, apt);
    cam_agg_kernel<<<dim3(NCAM, 8), 256, 0, stream>>>(ef, order_cam, off_cam, cam_agg);
    cam_proj<<<NCAM, 256, 0, stream>>>(cam_agg, CcamT, vcam, gcam, acam);
    e_kernel<<<eb, 256, 0, stream>>>(ci, pi, acam, apt, ebuf, bmax, bsum, E);
    softmax_combine<<<1, 1024, 0, stream>>>(bmax, bsum, gsm, eb);
    gemm_out<<<(NPT + 63) / 64, 256, 0, stream>>>(Ahi, Alo, Bhi, Blo, order_pt, off_pt,
                                                  ci, pi, ebuf, gsm, gcam, bfin, out, NPT);
}